// Round 1
// baseline (206.316 us; speedup 1.0000x reference)
//
#include <hip/hip_runtime.h>
#include <hip/hip_bf16.h>

// MultiHeadAttention B=4,S=4096,D=64,H=4,HD=16 on gfx950.
// softmax over QUERY axis => w[s,t] = E[s,t]/colsum[t], attended = E @ (V/colsum).
// Two MFMA passes recompute E (raw v_exp_f32).  Scores via 32x32x16 bf16 MFMA
// (K=16=HD exact).  PV consumes E directly as the B-operand; the implied k->t
// permutation is absorbed by pre-permuting v' in GLOBAL memory (k_vprep).
// R10: k_vprep precomputes v' = bf16(v * rcp(colsum)) in MFMA fragment order
// with XOR bank-swizzle baked into the global layout -> k_attn stages via
// global_load_lds (zero-VALU DMA), drops rcs LDS + f2bf staging + prefetch
// regs.  t-split 4 (grid 2048 = 8 blocks/CU, LDS 16.4KB, launch_bounds(256,8))
// doubles occupancy.  oproj sums 4 partials.

#define BB 4
#define SS 4096
#define DD 64
#define HH 4
#define HDD 16

typedef unsigned int u32;
typedef unsigned short u16;
typedef __attribute__((ext_vector_type(8))) short bfrag;     // 8 bf16
typedef __attribute__((ext_vector_type(4))) float floatx4;
typedef __attribute__((ext_vector_type(16))) float floatx16;
typedef __attribute__((ext_vector_type(2))) u32 u32x2;
typedef __attribute__((ext_vector_type(4))) u32 u32x4;

#define LOG2E 1.4426950408889634074f
#define QSCALE (LOG2E * 0.25f)

__device__ __forceinline__ float fexp2(float x) {   // raw v_exp_f32
#if __has_builtin(__builtin_amdgcn_exp2f)
  return __builtin_amdgcn_exp2f(x);
#else
  float r; asm("v_exp_f32 %0, %1" : "=v"(r) : "v"(x)); return r;
#endif
}
__device__ __forceinline__ float frcp(float x) {    // raw v_rcp_f32
#if __has_builtin(__builtin_amdgcn_rcpf)
  return __builtin_amdgcn_rcpf(x);
#else
  float r; asm("v_rcp_f32 %0, %1" : "=v"(r) : "v"(x)); return r;
#endif
}

__device__ __forceinline__ u16 f2bf(float f) {      // RNE
  u32 u = __builtin_bit_cast(u32, f);
  return (u16)((u + 0x7FFFu + ((u >> 16) & 1u)) >> 16);
}
// pack two fp32 -> bf16x2 by truncation (E>=0), single v_perm_b32
__device__ __forceinline__ u32 pack_bf(float lo, float hi) {
#if __has_builtin(__builtin_amdgcn_perm)
  return __builtin_amdgcn_perm(__builtin_bit_cast(u32, hi),
                               __builtin_bit_cast(u32, lo), 0x07060302u);
#else
  u32 a = __builtin_bit_cast(u32, lo);
  u32 b = __builtin_bit_cast(u32, hi);
  return (a >> 16) | (b & 0xFFFF0000u);
#endif
}

// global -> LDS DMA, 16B per lane.  LDS dest = wave-uniform base + lane*16.
__device__ __forceinline__ void gload_lds16(const u16* g, u16* l) {
  __builtin_amdgcn_global_load_lds(
      (const __attribute__((address_space(1))) void*)(g),
      (__attribute__((address_space(3))) void*)(l), 16, 0, 0);
}

// fragment column c (0..255 within a 256-t chunk) -> t within chunk.
// Within each 32-block: cols 0..7 -> t {0,1,2,3,8,9,10,11}, 8..15 -> +16,
// 16..23 -> +4, 24..31 -> +20  (matches 32x32x16 A/B k-slot <-> D-reg order).
__device__ __forceinline__ int tmap(int c) {
  int c5 = c & 31;
  return (c & ~31) + (c5 & 3) + ((c5 >> 2) & 1) * 8 + ((c5 >> 3) & 1) * 16
       + ((c5 >> 4) & 1) * 4;
}

// ---------------------------------------------------------------------------
// K1: projections. x[B,S,64] -> q bf16 (scaled, bias folded), k bf16, v fp32;
// layout [B,H,S,16].
// ---------------------------------------------------------------------------
__global__ __launch_bounds__(256) void k_proj(
    const float* __restrict__ x,
    const float* __restrict__ Wq, const float* __restrict__ bq,
    const float* __restrict__ Wk, const float* __restrict__ bk,
    const float* __restrict__ Wv, const float* __restrict__ bv,
    u16* __restrict__ qb, u16* __restrict__ kb, float* __restrict__ vf)
{
  __shared__ float xs[16 * 64];
  const int tid = threadIdx.x;
  const int blk = blockIdx.x;            // B*S/16 = 1024
  const int b   = blk >> 8;
  const int s0  = (blk & 255) << 4;
  ((float4*)xs)[tid] = ((const float4*)(x + ((size_t)b * SS + s0) * DD))[tid];
  __syncthreads();

  const int col = tid & 63, h = col >> 4, e = col & 15;
  const int rg  = tid >> 6;              // wave id; 4 rows each
  float aq[4] = {0,0,0,0}, ak[4] = {0,0,0,0}, av[4] = {0,0,0,0};
  const int wofs = h * (DD * HDD) + e;
#pragma unroll 4
  for (int d = 0; d < DD; ++d) {
    float wq = Wq[wofs + d * HDD];
    float wk = Wk[wofs + d * HDD];
    float wv = Wv[wofs + d * HDD];
    const float* xr = xs + (rg * 4) * 64 + d;
#pragma unroll
    for (int r = 0; r < 4; ++r) {
      float xv = xr[r * 64];
      aq[r] += xv * wq; ak[r] += xv * wk; av[r] += xv * wv;
    }
  }
  const float bqv = bq[col], bkv = bk[col], bvv = bv[col];
  size_t base = ((size_t)(b * HH + h) * SS + (s0 + rg * 4)) * HDD + e;
#pragma unroll
  for (int r = 0; r < 4; ++r) {
    qb[base + r * HDD] = f2bf((aq[r] + bqv) * QSCALE);
    kb[base + r * HDD] = f2bf(ak[r] + bkv);
    vf[base + r * HDD] = av[r] + bvv;
  }
}

// ---------------------------------------------------------------------------
// K2: partial colsums.  mfma(Q, K): D[m=s][n=t], col=lane&31 -> t, so the
// s-reduction is IN-LANE (4 parallel accumulators) + one shfl_xor(32).
// Wave owns 32 t; streams a 1024-s chunk.
// ---------------------------------------------------------------------------
__global__ __launch_bounds__(256, 8) void k_colsum(
    const u16* __restrict__ qb, const u16* __restrict__ kb,
    float* __restrict__ csp)
{
  const int tid = threadIdx.x;
  const int lane = tid & 63, w = tid >> 6;
  const int l31 = lane & 31, hl = lane >> 5;
  const int bh = blockIdx.z, chunk = blockIdx.y;
  const int t0 = blockIdx.x * 128 + w * 32;
  const size_t base = (size_t)bh * (SS * HDD);

  const bfrag kf = *(const bfrag*)(kb + base + (size_t)(t0 + l31) * HDD + hl * 8);
  const u16* qp = qb + base + (size_t)l31 * HDD + hl * 8;
  const floatx16 z16 = {0.f};
  float c0 = 0.f, c1 = 0.f, c2 = 0.f, c3 = 0.f;
  const int s0 = chunk * 1024;
#pragma unroll 2
  for (int s = s0; s < s0 + 1024; s += 32) {
    bfrag qfr = *(const bfrag*)(qp + (size_t)s * HDD);
    floatx16 d = __builtin_amdgcn_mfma_f32_32x32x16_bf16(qfr, kf, z16, 0, 0, 0);
#pragma unroll
    for (int i = 0; i < 4; ++i) {
      c0 += fexp2(d[4 * i + 0]);
      c1 += fexp2(d[4 * i + 1]);
      c2 += fexp2(d[4 * i + 2]);
      c3 += fexp2(d[4 * i + 3]);
    }
  }
  float c = (c0 + c1) + (c2 + c3);
  c += __shfl_xor(c, 32, 64);
  if (hl == 0)
    csp[((size_t)bh * 4 + chunk) * SS + t0 + l31] = c;
}

// ---------------------------------------------------------------------------
// K2.5: v' = bf16(v * rcp(colsum)) written to global in the EXACT linear
// order k_attn's LDS wants: vp[bh][chunk16][flat 4096 u16], flat index =
// e*256 + ((cc ^ (e&7))<<3) + (c&7)  with cc = c>>3 and fragment column c.
// The XOR term is the LDS bank swizzle (rows stride 512B would otherwise
// alias bank groups); it is baked here so k_attn's DMA stays linear.
// ---------------------------------------------------------------------------
__global__ __launch_bounds__(256) void k_vprep(
    const float* __restrict__ vf, const float* __restrict__ csp,
    u16* __restrict__ vp)
{
  __shared__ float rcls[256];
  const int tid = threadIdx.x;
  const int chunk = blockIdx.x;          // 0..15
  const int bh = blockIdx.y;             // 0..15
  const int t0 = chunk << 8;
  {
    const float* cp = csp + (size_t)bh * 4 * SS + t0 + tid;
    rcls[tid] = frcp(cp[0] + cp[SS] + cp[2 * SS] + cp[3 * SS]);
  }
  __syncthreads();
  const float* vb = vf + ((size_t)bh * SS + t0) * HDD;
  u16* outb = vp + ((size_t)bh * 16 + chunk) * 4096;
#pragma unroll
  for (int gi = 0; gi < 2; ++gi) {
    const int g = gi * 256 + tid;        // 0..511 groups of 8 u16
    const int e = g >> 5, gg = g & 31;
    const int cbase = (gg ^ (e & 7)) << 3;   // un-swizzled column base
    u32 r[4];
#pragma unroll
    for (int jj = 0; jj < 4; ++jj) {
      int ta = tmap(cbase + 2 * jj);
      int tb = tmap(cbase + 2 * jj + 1);
      u16 lo = f2bf(vb[ta * HDD + e] * rcls[ta]);
      u16 hi = f2bf(vb[tb * HDD + e] * rcls[tb]);
      r[jj] = (u32)lo | ((u32)hi << 16);
    }
    u32x4 vv = {r[0], r[1], r[2], r[3]};
    *(u32x4*)(outb + g * 8) = vv;
  }
}

// ---------------------------------------------------------------------------
// K3: attended partials = E @ v' over a 1024-t quarter: four 256-t chunks,
// double-buffered via global_load_lds (2 x 16B DMA per thread per chunk,
// zero VALU staging).  One barrier per chunk (syncthreads drains vmcnt).
// Inner loop per 32 t: 1 coalesced kf load, 1 score MFMA D'[t][s], 16 v_exp,
// 8 v_perm packs, 2 swizzled ds_read_b128, 2 PV MFMA.
// LDS 16.4 KB; grid 2048 = 8 blocks/CU; launch_bounds(256,8) -> VGPR<=64.
// ---------------------------------------------------------------------------
__global__ __launch_bounds__(256, 8) void k_attn(
    const u16* __restrict__ qb, const u16* __restrict__ kb,
    const u16* __restrict__ vp, float* __restrict__ attp)
{
  __shared__ __align__(16) u16 vls[2][4096];       // 2 x 8 KB
  const int tid  = threadIdx.x;
  const int lane = tid & 63, w = tid >> 6;
  const int l31 = lane & 31, hl = lane >> 5;
  const int bh = blockIdx.z, b = bh >> 2, h = bh & 3;
  const int tq = blockIdx.y;                       // 0..3 (t-quarter)
  const int s0 = blockIdx.x * 128 + w * 32;
  const size_t base = (size_t)bh * (SS * HDD);

  const bfrag qf = *(const bfrag*)(qb + base + (size_t)(s0 + l31) * HDD + hl * 8);
  const u16* kp = kb + base + ((size_t)tq * 1024 + l31) * HDD + hl * 8;
  const floatx16 z16 = {0.f};
  floatx16 acc = {0.f};

  const u16* vsrc = vp + ((size_t)bh * 16 + tq * 4) * 4096;

  // stage chunk 0: wave w covers u16 [w*1024, w*1024+1024)
  {
    const u16* gs = vsrc + w * 1024 + lane * 8;
    u16* ls = &vls[0][0] + w * 1024;
    gload_lds16(gs, ls);
    gload_lds16(gs + 512, ls + 512);
  }
  __syncthreads();

#pragma unroll
  for (int ch = 0; ch < 4; ++ch) {
    // DMA next chunk into the other buffer (lands before the end barrier)
    if (ch < 3) {
      const u16* gs = vsrc + (ch + 1) * 4096 + w * 1024 + lane * 8;
      u16* ls = &vls[(ch + 1) & 1][0] + w * 1024;
      gload_lds16(gs, ls);
      gload_lds16(gs + 512, ls + 512);
    }

    const u16* vrow = &vls[ch & 1][0] + (l31 & 15) * 256;
    const int eb = l31 & 7;
    const int tb = ch * 256;
#pragma unroll 2
    for (int it = 0; it < 8; ++it) {
      bfrag kf = *(const bfrag*)(kp + (size_t)(tb + it * 32) * HDD);
      floatx16 d = __builtin_amdgcn_mfma_f32_32x32x16_bf16(kf, qf, z16, 0, 0, 0);
      u32 wr[8];
#pragma unroll
      for (int p = 0; p < 8; ++p)
        wr[p] = pack_bf(fexp2(d[2 * p]), fexp2(d[2 * p + 1]));
      const int cc0 = it * 4 + hl * 2;
      u32x4 af0 = *(const u32x4*)(vrow + ((cc0 ^ eb) << 3));
      u32x4 af1 = *(const u32x4*)(vrow + (((cc0 + 1) ^ eb) << 3));
      u32x4 ef0 = {wr[0], wr[1], wr[2], wr[3]};
      u32x4 ef1 = {wr[4], wr[5], wr[6], wr[7]};
      acc = __builtin_amdgcn_mfma_f32_32x32x16_bf16(
          __builtin_bit_cast(bfrag, af0), __builtin_bit_cast(bfrag, ef0), acc, 0, 0, 0);
      acc = __builtin_amdgcn_mfma_f32_32x32x16_bf16(
          __builtin_bit_cast(bfrag, af1), __builtin_bit_cast(bfrag, ef1), acc, 0, 0, 0);
    }
    __syncthreads();   // drains vmcnt -> next chunk's DMA is in LDS
  }

  // D[e][s]: col=l31 -> s; rows r=0..3 -> e=4hl+r, r=4..7 -> e=8+4hl+(r-4)
  float* ao = attp + (((size_t)tq * BB + b) * SS + s0 + l31) * (HH * HDD)
            + h * HDD + 4 * hl;
  float4 lo4 = {acc[0], acc[1], acc[2], acc[3]};
  float4 hi4 = {acc[4], acc[5], acc[6], acc[7]};
  *(float4*)ao       = lo4;
  *(float4*)(ao + 8) = hi4;
}

// ---------------------------------------------------------------------------
// K4: out_pre = (sum of 4 attended partials) @ Wo + bo, fused partial expsum
// over each block's 8 rows -> part[b][512][64].  Wo staged in LDS.
// ---------------------------------------------------------------------------
__global__ __launch_bounds__(256) void k_oproj(
    const float* __restrict__ att, const float* __restrict__ Wo,
    const float* __restrict__ bo, float* __restrict__ outp,
    float* __restrict__ part)
{
  __shared__ float wols[64 * 64];
  __shared__ float red[4][64];
  const int tid = threadIdx.x;
  const int blk = blockIdx.x;            // 2048
  const int b = blk >> 9, s0 = (blk & 511) << 3;
#pragma unroll
  for (int i = 0; i < 4; ++i)
    ((float4*)wols)[tid + 256 * i] = ((const float4*)Wo)[tid + 256 * i];
  __syncthreads();

  const int d = tid & 63, sg = tid >> 6;
  const float bov = bo[d];
  const size_t so = (size_t)BB * SS * 16;   // t-quarter stride in floatx4 units
  float es = 0.f;
#pragma unroll
  for (int r = 0; r < 2; ++r) {
    int s = s0 + sg * 2 + r;
    const floatx4* row = (const floatx4*)(att + ((size_t)b * SS + s) * 64);
    float acc = bov;
#pragma unroll
    for (int j = 0; j < 16; ++j) {
      floatx4 c = (row[j] + row[j + so]) + (row[j + 2 * so] + row[j + 3 * so]);
      acc += c[0] * wols[(4*j+0)*64 + d] + c[1] * wols[(4*j+1)*64 + d]
           + c[2] * wols[(4*j+2)*64 + d] + c[3] * wols[(4*j+3)*64 + d];
    }
    outp[((size_t)b * SS + s) * 64 + d] = acc;
    es += fexp2(acc * LOG2E);
  }
  red[sg][d] = es;
  __syncthreads();
  if (tid < 64)
    part[((size_t)b * 512 + (blk & 511)) * 64 + tid] =
        red[0][tid] + red[1][tid] + red[2][tid] + red[3][tid];
}

// ---------------------------------------------------------------------------
// K5: out = exp(out_pre) * rcp(sum_s exp(out_pre))  (512 partials per (b,d))
// ---------------------------------------------------------------------------
__global__ __launch_bounds__(256) void k_softmax(
    const float* __restrict__ outp, const float* __restrict__ part,
    float* __restrict__ out)
{
  __shared__ float red[4][64];
  __shared__ float rs[64];
  const int tid = threadIdx.x, d = tid & 63, sg = tid >> 6;
  const int st = blockIdx.x;             // 64 s-tiles of 64
  const int b = blockIdx.y;
  {
    float e = 0.f;
    const float* pp = part + ((size_t)b * 512 + sg * 128) * 64 + d;
#pragma unroll 8
    for (int c = 0; c < 128; ++c) e += pp[c * 64];
    red[sg][d] = e;
  }
  __syncthreads();
  if (tid < 64)
    rs[tid] = frcp(red[0][tid] + red[1][tid] + red[2][tid] + red[3][tid]);
  __syncthreads();
  const float r = rs[d];
  const size_t rowbase = ((size_t)b * SS + st * 64 + sg * 16) * 64 + d;
#pragma unroll 4
  for (int i = 0; i < 16; ++i)
    out[rowbase + i * 64] = fexp2(outp[rowbase + i * 64] * LOG2E) * r;
}

// ---------------------------------------------------------------------------
extern "C" void kernel_launch(void* const* d_in, const int* in_sizes, int n_in,
                              void* d_out, int out_size, void* d_ws, size_t ws_size,
                              hipStream_t stream) {
  const float* x  = (const float*)d_in[0];
  const float* Wq = (const float*)d_in[1];
  const float* bq = (const float*)d_in[2];
  const float* Wk = (const float*)d_in[3];
  const float* bk = (const float*)d_in[4];
  const float* Wv = (const float*)d_in[5];
  const float* bv = (const float*)d_in[6];
  const float* Wo = (const float*)d_in[7];
  const float* bo = (const float*)d_in[8];

  char* ws = (char*)d_ws;
  constexpr size_t QB_OFF  = 0;                    // 2 MiB u16
  constexpr size_t KB_OFF  = (size_t)2  << 20;     // 2 MiB u16
  constexpr size_t VF_OFF  = (size_t)4  << 20;     // 4 MiB f32
  constexpr size_t CSP_OFF = (size_t)8  << 20;     // 1 MiB f32 (4 partials)
  constexpr size_t VP_OFF  = (size_t)9  << 20;     // 2 MiB u16 (v' fragments)
  constexpr size_t ATT_OFF = (size_t)11 << 20;     // 16 MiB f32 (4 partials)
  constexpr size_t OUT_OFF = (size_t)27 << 20;     // 4 MiB f32
  constexpr size_t PT_OFF  = (size_t)31 << 20;     // 512 KiB f32

  u16*   qb   = (u16*)  (ws + QB_OFF);
  u16*   kb   = (u16*)  (ws + KB_OFF);
  float* vf   = (float*)(ws + VF_OFF);
  float* csp  = (float*)(ws + CSP_OFF);
  u16*   vpb  = (u16*)  (ws + VP_OFF);
  float* attp = (float*)(ws + ATT_OFF);
  float* outp = (float*)(ws + OUT_OFF);
  float* part = (float*)(ws + PT_OFF);
  float* out  = (float*)d_out;

  hipLaunchKernelGGL(k_proj,    dim3(1024),       dim3(256), 0, stream,
                     x, Wq, bq, Wk, bk, Wv, bv, qb, kb, vf);
  hipLaunchKernelGGL(k_colsum,  dim3(32, 4, 16),  dim3(256), 0, stream, qb, kb, csp);
  hipLaunchKernelGGL(k_vprep,   dim3(16, 16),     dim3(256), 0, stream, vf, csp, vpb);
  hipLaunchKernelGGL(k_attn,    dim3(32, 4, 16),  dim3(256), 0, stream,
                     qb, kb, vpb, attp);
  hipLaunchKernelGGL(k_oproj,   dim3(2048),       dim3(256), 0, stream,
                     attp, Wo, bo, outp, part);
  hipLaunchKernelGGL(k_softmax, dim3(64, 4),      dim3(256), 0, stream, outp, part, out);
}

// Round 2
// 202.105 us; speedup vs baseline: 1.0208x; 1.0208x over previous
//
#include <hip/hip_runtime.h>
#include <hip/hip_bf16.h>

// MultiHeadAttention B=4,S=4096,D=64,H=4,HD=16 on gfx950.
// softmax over QUERY axis => w[s,t] = E[s,t]/colsum[t], attended = E @ (V/colsum).
// Two MFMA passes recompute E (raw v_exp_f32).  Scores via 32x32x16 bf16 MFMA
// (K=16=HD exact).  PV consumes E directly as the B-operand; the implied k->t
// permutation is absorbed by pre-permuting v' in GLOBAL memory (k_vprep).
// R11: k_attn was latency-bound, not TLP-bound (VALUBusy pinned ~47% at both
// 30% and 47% occupancy; VGPR=32 under lb(256,8) left no room to pipeline the
// per-iter kf load).  Fix: lb(256,4) + rolling 8-slot kf register prefetch
// (each iter consumes kfr[it], issues next chunk's load into the slot -> one
// full chunk of latency cover).  t-split back to 2 (grid 1024 = 4 blocks/CU,
// attp 8MB).  k_vprep gathers from LDS-staged tile instead of global.
// k_colsum gets a 2-deep rolling qfr prefetch.

#define BB 4
#define SS 4096
#define DD 64
#define HH 4
#define HDD 16

typedef unsigned int u32;
typedef unsigned short u16;
typedef __attribute__((ext_vector_type(8))) short bfrag;     // 8 bf16
typedef __attribute__((ext_vector_type(4))) float floatx4;
typedef __attribute__((ext_vector_type(16))) float floatx16;
typedef __attribute__((ext_vector_type(2))) u32 u32x2;
typedef __attribute__((ext_vector_type(4))) u32 u32x4;

#define LOG2E 1.4426950408889634074f
#define QSCALE (LOG2E * 0.25f)

__device__ __forceinline__ float fexp2(float x) {   // raw v_exp_f32
#if __has_builtin(__builtin_amdgcn_exp2f)
  return __builtin_amdgcn_exp2f(x);
#else
  float r; asm("v_exp_f32 %0, %1" : "=v"(r) : "v"(x)); return r;
#endif
}
__device__ __forceinline__ float frcp(float x) {    // raw v_rcp_f32
#if __has_builtin(__builtin_amdgcn_rcpf)
  return __builtin_amdgcn_rcpf(x);
#else
  float r; asm("v_rcp_f32 %0, %1" : "=v"(r) : "v"(x)); return r;
#endif
}

__device__ __forceinline__ u16 f2bf(float f) {      // RNE
  u32 u = __builtin_bit_cast(u32, f);
  return (u16)((u + 0x7FFFu + ((u >> 16) & 1u)) >> 16);
}
// pack two fp32 -> bf16x2 by truncation (E>=0), single v_perm_b32
__device__ __forceinline__ u32 pack_bf(float lo, float hi) {
#if __has_builtin(__builtin_amdgcn_perm)
  return __builtin_amdgcn_perm(__builtin_bit_cast(u32, hi),
                               __builtin_bit_cast(u32, lo), 0x07060302u);
#else
  u32 a = __builtin_bit_cast(u32, lo);
  u32 b = __builtin_bit_cast(u32, hi);
  return (a >> 16) | (b & 0xFFFF0000u);
#endif
}

// global -> LDS DMA, 16B per lane.  LDS dest = wave-uniform base + lane*16.
__device__ __forceinline__ void gload_lds16(const u16* g, u16* l) {
  __builtin_amdgcn_global_load_lds(
      (const __attribute__((address_space(1))) void*)(g),
      (__attribute__((address_space(3))) void*)(l), 16, 0, 0);
}

// fragment column c (0..255 within a 256-t chunk) -> t within chunk.
__device__ __forceinline__ int tmap(int c) {
  int c5 = c & 31;
  return (c & ~31) + (c5 & 3) + ((c5 >> 2) & 1) * 8 + ((c5 >> 3) & 1) * 16
       + ((c5 >> 4) & 1) * 4;
}

// ---------------------------------------------------------------------------
// K1: projections. x[B,S,64] -> q bf16 (scaled, bias folded), k bf16, v fp32;
// layout [B,H,S,16].
// ---------------------------------------------------------------------------
__global__ __launch_bounds__(256) void k_proj(
    const float* __restrict__ x,
    const float* __restrict__ Wq, const float* __restrict__ bq,
    const float* __restrict__ Wk, const float* __restrict__ bk,
    const float* __restrict__ Wv, const float* __restrict__ bv,
    u16* __restrict__ qb, u16* __restrict__ kb, float* __restrict__ vf)
{
  __shared__ float xs[16 * 64];
  const int tid = threadIdx.x;
  const int blk = blockIdx.x;            // B*S/16 = 1024
  const int b   = blk >> 8;
  const int s0  = (blk & 255) << 4;
  ((float4*)xs)[tid] = ((const float4*)(x + ((size_t)b * SS + s0) * DD))[tid];
  __syncthreads();

  const int col = tid & 63, h = col >> 4, e = col & 15;
  const int rg  = tid >> 6;              // wave id; 4 rows each
  float aq[4] = {0,0,0,0}, ak[4] = {0,0,0,0}, av[4] = {0,0,0,0};
  const int wofs = h * (DD * HDD) + e;
#pragma unroll 4
  for (int d = 0; d < DD; ++d) {
    float wq = Wq[wofs + d * HDD];
    float wk = Wk[wofs + d * HDD];
    float wv = Wv[wofs + d * HDD];
    const float* xr = xs + (rg * 4) * 64 + d;
#pragma unroll
    for (int r = 0; r < 4; ++r) {
      float xv = xr[r * 64];
      aq[r] += xv * wq; ak[r] += xv * wk; av[r] += xv * wv;
    }
  }
  const float bqv = bq[col], bkv = bk[col], bvv = bv[col];
  size_t base = ((size_t)(b * HH + h) * SS + (s0 + rg * 4)) * HDD + e;
#pragma unroll
  for (int r = 0; r < 4; ++r) {
    qb[base + r * HDD] = f2bf((aq[r] + bqv) * QSCALE);
    kb[base + r * HDD] = f2bf(ak[r] + bkv);
    vf[base + r * HDD] = av[r] + bvv;
  }
}

// ---------------------------------------------------------------------------
// K2: partial colsums.  mfma(Q, K): D[m=s][n=t], col=lane&31 -> t, so the
// s-reduction is IN-LANE (4 parallel accumulators) + one shfl_xor(32).
// Wave owns 32 t; streams a 1024-s chunk with a 2-deep rolling qfr prefetch.
// ---------------------------------------------------------------------------
__global__ __launch_bounds__(256, 8) void k_colsum(
    const u16* __restrict__ qb, const u16* __restrict__ kb,
    float* __restrict__ csp)
{
  const int tid = threadIdx.x;
  const int lane = tid & 63, w = tid >> 6;
  const int l31 = lane & 31, hl = lane >> 5;
  const int bh = blockIdx.z, chunk = blockIdx.y;
  const int t0 = blockIdx.x * 128 + w * 32;
  const size_t base = (size_t)bh * (SS * HDD);

  const bfrag kf = *(const bfrag*)(kb + base + (size_t)(t0 + l31) * HDD + hl * 8);
  const u16* qp = qb + base + ((size_t)chunk * 1024 + l31) * HDD + hl * 8;
  const floatx16 z16 = {0.f};
  float c0 = 0.f, c1 = 0.f, c2 = 0.f, c3 = 0.f;

  bfrag q2[2];
  q2[0] = *(const bfrag*)(qp);
  q2[1] = *(const bfrag*)(qp + (size_t)32 * HDD);
#pragma unroll 4
  for (int i = 0; i < 32; ++i) {
    bfrag qa = q2[i & 1];
    if (i < 30)
      q2[i & 1] = *(const bfrag*)(qp + (size_t)((i + 2) * 32) * HDD);
    floatx16 d = __builtin_amdgcn_mfma_f32_32x32x16_bf16(qa, kf, z16, 0, 0, 0);
#pragma unroll
    for (int j = 0; j < 4; ++j) {
      c0 += fexp2(d[4 * j + 0]);
      c1 += fexp2(d[4 * j + 1]);
      c2 += fexp2(d[4 * j + 2]);
      c3 += fexp2(d[4 * j + 3]);
    }
  }
  float c = (c0 + c1) + (c2 + c3);
  c += __shfl_xor(c, 32, 64);
  if (hl == 0)
    csp[((size_t)bh * 4 + chunk) * SS + t0 + l31] = c;
}

// ---------------------------------------------------------------------------
// K2.5: v' = bf16(v * rcp(colsum)) written to global in the EXACT linear
// order k_attn's LDS wants: vp[bh][chunk16][flat 4096 u16], flat index =
// e*256 + ((cc ^ (e&7))<<3) + (c&7).  v-tile staged in LDS (coalesced float4
// in, scattered LDS gather out) -- the gather never touches global.
// ---------------------------------------------------------------------------
__global__ __launch_bounds__(256) void k_vprep(
    const float* __restrict__ vf, const float* __restrict__ csp,
    u16* __restrict__ vp)
{
  __shared__ float vstage[256 * 16];     // [t][e], 16 KB
  __shared__ float rcls[256];
  const int tid = threadIdx.x;
  const int chunk = blockIdx.x;          // 0..15
  const int bh = blockIdx.y;             // 0..15
  const int t0 = chunk << 8;
  {
    const float4* src = (const float4*)(vf + ((size_t)bh * SS + t0) * HDD);
    float4* dst = (float4*)vstage;
#pragma unroll
    for (int i = 0; i < 4; ++i) dst[tid + 256 * i] = src[tid + 256 * i];
    const float* cp = csp + (size_t)bh * 4 * SS + t0 + tid;
    rcls[tid] = frcp(cp[0] + cp[SS] + cp[2 * SS] + cp[3 * SS]);
  }
  __syncthreads();
  u16* outb = vp + ((size_t)bh * 16 + chunk) * 4096;
#pragma unroll
  for (int gi = 0; gi < 2; ++gi) {
    const int g = gi * 256 + tid;        // 0..511 groups of 8 u16
    const int e = g >> 5, gg = g & 31;
    const int cbase = (gg ^ (e & 7)) << 3;
    u32 r[4];
#pragma unroll
    for (int jj = 0; jj < 4; ++jj) {
      int ta = tmap(cbase + 2 * jj);
      int tb = tmap(cbase + 2 * jj + 1);
      u16 lo = f2bf(vstage[ta * 16 + e] * rcls[ta]);
      u16 hi = f2bf(vstage[tb * 16 + e] * rcls[tb]);
      r[jj] = (u32)lo | ((u32)hi << 16);
    }
    u32x4 vv = {r[0], r[1], r[2], r[3]};
    *(u32x4*)(outb + g * 8) = vv;
  }
}

// ---------------------------------------------------------------------------
// K3: attended partials = E @ v' over a 2048-t half: eight 256-t chunks,
// double-buffered via global_load_lds (zero-VALU v staging) + rolling 8-slot
// kf register prefetch (each iter consumes kfr[it] then issues next chunk's
// load into the slot -> ~1 chunk of compute covers the L2 latency).
// Inner loop per 32 t: 1 score MFMA D'[t][s], 16 v_exp, 8 v_perm packs,
// 2 swizzled ds_read_b128, 2 PV MFMA.
// LDS 16.4 KB; grid 1024 = 4 blocks/CU exact; lb(256,4) -> 128-reg budget.
// ---------------------------------------------------------------------------
__global__ __launch_bounds__(256, 4) void k_attn(
    const u16* __restrict__ qb, const u16* __restrict__ kb,
    const u16* __restrict__ vp, float* __restrict__ attp)
{
  __shared__ __align__(16) u16 vls[2][4096];       // 2 x 8 KB
  const int tid  = threadIdx.x;
  const int lane = tid & 63, w = tid >> 6;
  const int l31 = lane & 31, hl = lane >> 5;
  const int bh = blockIdx.z, b = bh >> 2, h = bh & 3;
  const int tph = blockIdx.y;                      // 0..1 (t-half)
  const int s0 = blockIdx.x * 128 + w * 32;
  const size_t base = (size_t)bh * (SS * HDD);

  const bfrag qf = *(const bfrag*)(qb + base + (size_t)(s0 + l31) * HDD + hl * 8);
  const u16* kp = kb + base + ((size_t)tph * 2048 + l31) * HDD + hl * 8;
  const floatx16 z16 = {0.f};
  floatx16 acc = {0.f};

  const u16* vsrc = vp + ((size_t)bh * 16 + tph * 8) * 4096;

  // stage chunk 0: wave w covers u16 [w*1024, w*1024+1024)
  {
    const u16* gs = vsrc + w * 1024 + lane * 8;
    u16* ls = &vls[0][0] + w * 1024;
    gload_lds16(gs, ls);
    gload_lds16(gs + 512, ls + 512);
  }
  // prefetch chunk 0's eight kf fragments into registers
  bfrag kfr[8];
#pragma unroll
  for (int it = 0; it < 8; ++it)
    kfr[it] = *(const bfrag*)(kp + (size_t)(it * 32) * HDD);
  __syncthreads();

#pragma unroll
  for (int ch = 0; ch < 8; ++ch) {
    // DMA next chunk into the other buffer (lands before the end barrier)
    if (ch < 7) {
      const u16* gs = vsrc + (ch + 1) * 4096 + w * 1024 + lane * 8;
      u16* ls = &vls[(ch + 1) & 1][0] + w * 1024;
      gload_lds16(gs, ls);
      gload_lds16(gs + 512, ls + 512);
    }

    const u16* vrow = &vls[ch & 1][0] + (l31 & 15) * 256;
    const int eb = l31 & 7;
#pragma unroll
    for (int it = 0; it < 8; ++it) {
      bfrag kf = kfr[it];
      if (ch < 7)    // rolling prefetch: next chunk's fragment, same slot
        kfr[it] = *(const bfrag*)(kp + (size_t)((ch + 1) * 256 + it * 32) * HDD);
      floatx16 d = __builtin_amdgcn_mfma_f32_32x32x16_bf16(kf, qf, z16, 0, 0, 0);
      u32 wr[8];
#pragma unroll
      for (int p = 0; p < 8; ++p)
        wr[p] = pack_bf(fexp2(d[2 * p]), fexp2(d[2 * p + 1]));
      const int cc0 = it * 4 + hl * 2;
      u32x4 af0 = *(const u32x4*)(vrow + ((cc0 ^ eb) << 3));
      u32x4 af1 = *(const u32x4*)(vrow + (((cc0 + 1) ^ eb) << 3));
      u32x4 ef0 = {wr[0], wr[1], wr[2], wr[3]};
      u32x4 ef1 = {wr[4], wr[5], wr[6], wr[7]};
      acc = __builtin_amdgcn_mfma_f32_32x32x16_bf16(
          __builtin_bit_cast(bfrag, af0), __builtin_bit_cast(bfrag, ef0), acc, 0, 0, 0);
      acc = __builtin_amdgcn_mfma_f32_32x32x16_bf16(
          __builtin_bit_cast(bfrag, af1), __builtin_bit_cast(bfrag, ef1), acc, 0, 0, 0);
    }
    __syncthreads();   // drains vmcnt -> next chunk's DMA is in LDS
  }

  // D[e][s]: col=l31 -> s; rows r=0..3 -> e=4hl+r, r=4..7 -> e=8+4hl+(r-4)
  float* ao = attp + (((size_t)tph * BB + b) * SS + s0 + l31) * (HH * HDD)
            + h * HDD + 4 * hl;
  float4 lo4 = {acc[0], acc[1], acc[2], acc[3]};
  float4 hi4 = {acc[4], acc[5], acc[6], acc[7]};
  *(float4*)ao       = lo4;
  *(float4*)(ao + 8) = hi4;
}

// ---------------------------------------------------------------------------
// K4: out_pre = (sum of 2 attended partials) @ Wo + bo, fused partial expsum
// over each block's 8 rows -> part[b][512][64].  Wo staged in LDS.
// ---------------------------------------------------------------------------
__global__ __launch_bounds__(256) void k_oproj(
    const float* __restrict__ att, const float* __restrict__ Wo,
    const float* __restrict__ bo, float* __restrict__ outp,
    float* __restrict__ part)
{
  __shared__ float wols[64 * 64];
  __shared__ float red[4][64];
  const int tid = threadIdx.x;
  const int blk = blockIdx.x;            // 2048
  const int b = blk >> 9, s0 = (blk & 511) << 3;
#pragma unroll
  for (int i = 0; i < 4; ++i)
    ((float4*)wols)[tid + 256 * i] = ((const float4*)Wo)[tid + 256 * i];
  __syncthreads();

  const int d = tid & 63, sg = tid >> 6;
  const float bov = bo[d];
  const size_t so = (size_t)BB * SS * 16;   // t-half stride in floatx4 units
  float es = 0.f;
#pragma unroll
  for (int r = 0; r < 2; ++r) {
    int s = s0 + sg * 2 + r;
    const floatx4* row = (const floatx4*)(att + ((size_t)b * SS + s) * 64);
    float acc = bov;
#pragma unroll
    for (int j = 0; j < 16; ++j) {
      floatx4 c = row[j] + row[j + so];
      acc += c[0] * wols[(4*j+0)*64 + d] + c[1] * wols[(4*j+1)*64 + d]
           + c[2] * wols[(4*j+2)*64 + d] + c[3] * wols[(4*j+3)*64 + d];
    }
    outp[((size_t)b * SS + s) * 64 + d] = acc;
    es += fexp2(acc * LOG2E);
  }
  red[sg][d] = es;
  __syncthreads();
  if (tid < 64)
    part[((size_t)b * 512 + (blk & 511)) * 64 + tid] =
        red[0][tid] + red[1][tid] + red[2][tid] + red[3][tid];
}

// ---------------------------------------------------------------------------
// K5: out = exp(out_pre) * rcp(sum_s exp(out_pre))  (512 partials per (b,d))
// ---------------------------------------------------------------------------
__global__ __launch_bounds__(256) void k_softmax(
    const float* __restrict__ outp, const float* __restrict__ part,
    float* __restrict__ out)
{
  __shared__ float red[4][64];
  __shared__ float rs[64];
  const int tid = threadIdx.x, d = tid & 63, sg = tid >> 6;
  const int st = blockIdx.x;             // 64 s-tiles of 64
  const int b = blockIdx.y;
  {
    float e = 0.f;
    const float* pp = part + ((size_t)b * 512 + sg * 128) * 64 + d;
#pragma unroll 8
    for (int c = 0; c < 128; ++c) e += pp[c * 64];
    red[sg][d] = e;
  }
  __syncthreads();
  if (tid < 64)
    rs[tid] = frcp(red[0][tid] + red[1][tid] + red[2][tid] + red[3][tid]);
  __syncthreads();
  const float r = rs[d];
  const size_t rowbase = ((size_t)b * SS + st * 64 + sg * 16) * 64 + d;
#pragma unroll 4
  for (int i = 0; i < 16; ++i)
    out[rowbase + i * 64] = fexp2(outp[rowbase + i * 64] * LOG2E) * r;
}

// ---------------------------------------------------------------------------
extern "C" void kernel_launch(void* const* d_in, const int* in_sizes, int n_in,
                              void* d_out, int out_size, void* d_ws, size_t ws_size,
                              hipStream_t stream) {
  const float* x  = (const float*)d_in[0];
  const float* Wq = (const float*)d_in[1];
  const float* bq = (const float*)d_in[2];
  const float* Wk = (const float*)d_in[3];
  const float* bk = (const float*)d_in[4];
  const float* Wv = (const float*)d_in[5];
  const float* bv = (const float*)d_in[6];
  const float* Wo = (const float*)d_in[7];
  const float* bo = (const float*)d_in[8];

  char* ws = (char*)d_ws;
  constexpr size_t QB_OFF  = 0;                    // 2 MiB u16
  constexpr size_t KB_OFF  = (size_t)2  << 20;     // 2 MiB u16
  constexpr size_t VF_OFF  = (size_t)4  << 20;     // 4 MiB f32
  constexpr size_t CSP_OFF = (size_t)8  << 20;     // 1 MiB f32 (4 partials)
  constexpr size_t VP_OFF  = (size_t)9  << 20;     // 2 MiB u16 (v' fragments)
  constexpr size_t ATT_OFF = (size_t)11 << 20;     // 8 MiB f32 (2 partials)
  constexpr size_t OUT_OFF = (size_t)19 << 20;     // 4 MiB f32
  constexpr size_t PT_OFF  = (size_t)23 << 20;     // 512 KiB f32

  u16*   qb   = (u16*)  (ws + QB_OFF);
  u16*   kb   = (u16*)  (ws + KB_OFF);
  float* vf   = (float*)(ws + VF_OFF);
  float* csp  = (float*)(ws + CSP_OFF);
  u16*   vpb  = (u16*)  (ws + VP_OFF);
  float* attp = (float*)(ws + ATT_OFF);
  float* outp = (float*)(ws + OUT_OFF);
  float* part = (float*)(ws + PT_OFF);
  float* out  = (float*)d_out;

  hipLaunchKernelGGL(k_proj,    dim3(1024),       dim3(256), 0, stream,
                     x, Wq, bq, Wk, bk, Wv, bv, qb, kb, vf);
  hipLaunchKernelGGL(k_colsum,  dim3(32, 4, 16),  dim3(256), 0, stream, qb, kb, csp);
  hipLaunchKernelGGL(k_vprep,   dim3(16, 16),     dim3(256), 0, stream, vf, csp, vpb);
  hipLaunchKernelGGL(k_attn,    dim3(32, 2, 16),  dim3(256), 0, stream,
                     qb, kb, vpb, attp);
  hipLaunchKernelGGL(k_oproj,   dim3(2048),       dim3(256), 0, stream,
                     attp, Wo, bo, outp, part);
  hipLaunchKernelGGL(k_softmax, dim3(64, 4),      dim3(256), 0, stream, outp, part, out);
}

// Round 3
// 182.004 us; speedup vs baseline: 1.1336x; 1.1104x over previous
//
#include <hip/hip_runtime.h>
#include <hip/hip_bf16.h>

// MultiHeadAttention B=4,S=4096,D=64,H=4,HD=16 on gfx950.
// softmax over QUERY axis => w[s,t] = E[s,t]/colsum[t], attended = E @ (V/colsum).
// Two MFMA passes recompute E (raw v_exp_f32).  Scores via 32x32x16 bf16 MFMA
// (K=16=HD exact).  PV consumes E directly as the B-operand; the implied k->t
// permutation is absorbed by pre-permuting v' in GLOBAL memory (k_vprep).
// R12: R11's k_colsum q2[i&1] rolling prefetch spilled to scratch under the
// lb(256,8) 32-VGPR cap (WRITE_SIZE 44.5MB vs 1MB ideal, 52us).  Fix: colsum
// lb(256,4) (128-reg budget, still 4 blocks/CU) + 4-deep fully-unrolled
// prefetch in NAMED registers (all indices compile-time).  k_attn (lb(256,4)
// + rolling kf prefetch) and the rest unchanged from R11.

#define BB 4
#define SS 4096
#define DD 64
#define HH 4
#define HDD 16

typedef unsigned int u32;
typedef unsigned short u16;
typedef __attribute__((ext_vector_type(8))) short bfrag;     // 8 bf16
typedef __attribute__((ext_vector_type(4))) float floatx4;
typedef __attribute__((ext_vector_type(16))) float floatx16;
typedef __attribute__((ext_vector_type(2))) u32 u32x2;
typedef __attribute__((ext_vector_type(4))) u32 u32x4;

#define LOG2E 1.4426950408889634074f
#define QSCALE (LOG2E * 0.25f)

__device__ __forceinline__ float fexp2(float x) {   // raw v_exp_f32
#if __has_builtin(__builtin_amdgcn_exp2f)
  return __builtin_amdgcn_exp2f(x);
#else
  float r; asm("v_exp_f32 %0, %1" : "=v"(r) : "v"(x)); return r;
#endif
}
__device__ __forceinline__ float frcp(float x) {    // raw v_rcp_f32
#if __has_builtin(__builtin_amdgcn_rcpf)
  return __builtin_amdgcn_rcpf(x);
#else
  float r; asm("v_rcp_f32 %0, %1" : "=v"(r) : "v"(x)); return r;
#endif
}

__device__ __forceinline__ u16 f2bf(float f) {      // RNE
  u32 u = __builtin_bit_cast(u32, f);
  return (u16)((u + 0x7FFFu + ((u >> 16) & 1u)) >> 16);
}
// pack two fp32 -> bf16x2 by truncation (E>=0), single v_perm_b32
__device__ __forceinline__ u32 pack_bf(float lo, float hi) {
#if __has_builtin(__builtin_amdgcn_perm)
  return __builtin_amdgcn_perm(__builtin_bit_cast(u32, hi),
                               __builtin_bit_cast(u32, lo), 0x07060302u);
#else
  u32 a = __builtin_bit_cast(u32, lo);
  u32 b = __builtin_bit_cast(u32, hi);
  return (a >> 16) | (b & 0xFFFF0000u);
#endif
}

// global -> LDS DMA, 16B per lane.  LDS dest = wave-uniform base + lane*16.
__device__ __forceinline__ void gload_lds16(const u16* g, u16* l) {
  __builtin_amdgcn_global_load_lds(
      (const __attribute__((address_space(1))) void*)(g),
      (__attribute__((address_space(3))) void*)(l), 16, 0, 0);
}

// fragment column c (0..255 within a 256-t chunk) -> t within chunk.
__device__ __forceinline__ int tmap(int c) {
  int c5 = c & 31;
  return (c & ~31) + (c5 & 3) + ((c5 >> 2) & 1) * 8 + ((c5 >> 3) & 1) * 16
       + ((c5 >> 4) & 1) * 4;
}

// ---------------------------------------------------------------------------
// K1: projections. x[B,S,64] -> q bf16 (scaled, bias folded), k bf16, v fp32;
// layout [B,H,S,16].
// ---------------------------------------------------------------------------
__global__ __launch_bounds__(256) void k_proj(
    const float* __restrict__ x,
    const float* __restrict__ Wq, const float* __restrict__ bq,
    const float* __restrict__ Wk, const float* __restrict__ bk,
    const float* __restrict__ Wv, const float* __restrict__ bv,
    u16* __restrict__ qb, u16* __restrict__ kb, float* __restrict__ vf)
{
  __shared__ float xs[16 * 64];
  const int tid = threadIdx.x;
  const int blk = blockIdx.x;            // B*S/16 = 1024
  const int b   = blk >> 8;
  const int s0  = (blk & 255) << 4;
  ((float4*)xs)[tid] = ((const float4*)(x + ((size_t)b * SS + s0) * DD))[tid];
  __syncthreads();

  const int col = tid & 63, h = col >> 4, e = col & 15;
  const int rg  = tid >> 6;              // wave id; 4 rows each
  float aq[4] = {0,0,0,0}, ak[4] = {0,0,0,0}, av[4] = {0,0,0,0};
  const int wofs = h * (DD * HDD) + e;
#pragma unroll 4
  for (int d = 0; d < DD; ++d) {
    float wq = Wq[wofs + d * HDD];
    float wk = Wk[wofs + d * HDD];
    float wv = Wv[wofs + d * HDD];
    const float* xr = xs + (rg * 4) * 64 + d;
#pragma unroll
    for (int r = 0; r < 4; ++r) {
      float xv = xr[r * 64];
      aq[r] += xv * wq; ak[r] += xv * wk; av[r] += xv * wv;
    }
  }
  const float bqv = bq[col], bkv = bk[col], bvv = bv[col];
  size_t base = ((size_t)(b * HH + h) * SS + (s0 + rg * 4)) * HDD + e;
#pragma unroll
  for (int r = 0; r < 4; ++r) {
    qb[base + r * HDD] = f2bf((aq[r] + bqv) * QSCALE);
    kb[base + r * HDD] = f2bf(ak[r] + bkv);
    vf[base + r * HDD] = av[r] + bvv;
  }
}

// ---------------------------------------------------------------------------
// K2: partial colsums.  mfma(Q, K): D[m=s][n=t], col=lane&31 -> t, so the
// s-reduction is IN-LANE (4 parallel accumulators) + one shfl_xor(32).
// Wave owns 32 t; streams a 1024-s chunk.  4-deep prefetch in NAMED regs
// (compile-time indices only), lb(256,4) so nothing spills (~50 VGPR used).
// ---------------------------------------------------------------------------
__global__ __launch_bounds__(256, 4) void k_colsum(
    const u16* __restrict__ qb, const u16* __restrict__ kb,
    float* __restrict__ csp)
{
  const int tid = threadIdx.x;
  const int lane = tid & 63, w = tid >> 6;
  const int l31 = lane & 31, hl = lane >> 5;
  const int bh = blockIdx.z, chunk = blockIdx.y;
  const int t0 = blockIdx.x * 128 + w * 32;
  const size_t base = (size_t)bh * (SS * HDD);

  const bfrag kf = *(const bfrag*)(kb + base + (size_t)(t0 + l31) * HDD + hl * 8);
  const u16* qp = qb + base + ((size_t)chunk * 1024 + l31) * HDD + hl * 8;
  const floatx16 z16 = {0.f};
  float c0 = 0.f, c1 = 0.f, c2 = 0.f, c3 = 0.f;

#define LQ(i) (*(const bfrag*)(qp + (size_t)((i) * 32) * HDD))
#define ACCUM(dv)                                   \
  do {                                              \
    _Pragma("unroll")                               \
    for (int j = 0; j < 4; ++j) {                   \
      c0 += fexp2((dv)[4 * j + 0]);                 \
      c1 += fexp2((dv)[4 * j + 1]);                 \
      c2 += fexp2((dv)[4 * j + 2]);                 \
      c3 += fexp2((dv)[4 * j + 3]);                 \
    }                                               \
  } while (0)

  bfrag q0 = LQ(0), q1 = LQ(1), q2v = LQ(2), q3 = LQ(3);
#pragma unroll
  for (int i = 0; i < 32; i += 4) {
    {
      floatx16 d = __builtin_amdgcn_mfma_f32_32x32x16_bf16(q0, kf, z16, 0, 0, 0);
      if (i + 4 < 32) q0 = LQ(i + 4);
      ACCUM(d);
    }
    {
      floatx16 d = __builtin_amdgcn_mfma_f32_32x32x16_bf16(q1, kf, z16, 0, 0, 0);
      if (i + 5 < 32) q1 = LQ(i + 5);
      ACCUM(d);
    }
    {
      floatx16 d = __builtin_amdgcn_mfma_f32_32x32x16_bf16(q2v, kf, z16, 0, 0, 0);
      if (i + 6 < 32) q2v = LQ(i + 6);
      ACCUM(d);
    }
    {
      floatx16 d = __builtin_amdgcn_mfma_f32_32x32x16_bf16(q3, kf, z16, 0, 0, 0);
      if (i + 7 < 32) q3 = LQ(i + 7);
      ACCUM(d);
    }
  }
#undef LQ
#undef ACCUM

  float c = (c0 + c1) + (c2 + c3);
  c += __shfl_xor(c, 32, 64);
  if (hl == 0)
    csp[((size_t)bh * 4 + chunk) * SS + t0 + l31] = c;
}

// ---------------------------------------------------------------------------
// K2.5: v' = bf16(v * rcp(colsum)) written to global in the EXACT linear
// order k_attn's LDS wants: vp[bh][chunk16][flat 4096 u16], flat index =
// e*256 + ((cc ^ (e&7))<<3) + (c&7).  v-tile staged in LDS (coalesced float4
// in, scattered LDS gather out) -- the gather never touches global.
// ---------------------------------------------------------------------------
__global__ __launch_bounds__(256) void k_vprep(
    const float* __restrict__ vf, const float* __restrict__ csp,
    u16* __restrict__ vp)
{
  __shared__ float vstage[256 * 16];     // [t][e], 16 KB
  __shared__ float rcls[256];
  const int tid = threadIdx.x;
  const int chunk = blockIdx.x;          // 0..15
  const int bh = blockIdx.y;             // 0..15
  const int t0 = chunk << 8;
  {
    const float4* src = (const float4*)(vf + ((size_t)bh * SS + t0) * HDD);
    float4* dst = (float4*)vstage;
#pragma unroll
    for (int i = 0; i < 4; ++i) dst[tid + 256 * i] = src[tid + 256 * i];
    const float* cp = csp + (size_t)bh * 4 * SS + t0 + tid;
    rcls[tid] = frcp(cp[0] + cp[SS] + cp[2 * SS] + cp[3 * SS]);
  }
  __syncthreads();
  u16* outb = vp + ((size_t)bh * 16 + chunk) * 4096;
#pragma unroll
  for (int gi = 0; gi < 2; ++gi) {
    const int g = gi * 256 + tid;        // 0..511 groups of 8 u16
    const int e = g >> 5, gg = g & 31;
    const int cbase = (gg ^ (e & 7)) << 3;
    u32 r[4];
#pragma unroll
    for (int jj = 0; jj < 4; ++jj) {
      int ta = tmap(cbase + 2 * jj);
      int tb = tmap(cbase + 2 * jj + 1);
      u16 lo = f2bf(vstage[ta * 16 + e] * rcls[ta]);
      u16 hi = f2bf(vstage[tb * 16 + e] * rcls[tb]);
      r[jj] = (u32)lo | ((u32)hi << 16);
    }
    u32x4 vv = {r[0], r[1], r[2], r[3]};
    *(u32x4*)(outb + g * 8) = vv;
  }
}

// ---------------------------------------------------------------------------
// K3: attended partials = E @ v' over a 2048-t half: eight 256-t chunks,
// double-buffered via global_load_lds (zero-VALU v staging) + rolling 8-slot
// kf register prefetch (each iter consumes kfr[it] then issues next chunk's
// load into the slot -> ~1 chunk of compute covers the L2 latency).
// Inner loop per 32 t: 1 score MFMA D'[t][s], 16 v_exp, 8 v_perm packs,
// 2 swizzled ds_read_b128, 2 PV MFMA.
// LDS 16.4 KB; grid 1024 = 4 blocks/CU exact; lb(256,4) -> 128-reg budget.
// ---------------------------------------------------------------------------
__global__ __launch_bounds__(256, 4) void k_attn(
    const u16* __restrict__ qb, const u16* __restrict__ kb,
    const u16* __restrict__ vp, float* __restrict__ attp)
{
  __shared__ __align__(16) u16 vls[2][4096];       // 2 x 8 KB
  const int tid  = threadIdx.x;
  const int lane = tid & 63, w = tid >> 6;
  const int l31 = lane & 31, hl = lane >> 5;
  const int bh = blockIdx.z, b = bh >> 2, h = bh & 3;
  const int tph = blockIdx.y;                      // 0..1 (t-half)
  const int s0 = blockIdx.x * 128 + w * 32;
  const size_t base = (size_t)bh * (SS * HDD);

  const bfrag qf = *(const bfrag*)(qb + base + (size_t)(s0 + l31) * HDD + hl * 8);
  const u16* kp = kb + base + ((size_t)tph * 2048 + l31) * HDD + hl * 8;
  const floatx16 z16 = {0.f};
  floatx16 acc = {0.f};

  const u16* vsrc = vp + ((size_t)bh * 16 + tph * 8) * 4096;

  // stage chunk 0: wave w covers u16 [w*1024, w*1024+1024)
  {
    const u16* gs = vsrc + w * 1024 + lane * 8;
    u16* ls = &vls[0][0] + w * 1024;
    gload_lds16(gs, ls);
    gload_lds16(gs + 512, ls + 512);
  }
  // prefetch chunk 0's eight kf fragments into registers
  bfrag kfr[8];
#pragma unroll
  for (int it = 0; it < 8; ++it)
    kfr[it] = *(const bfrag*)(kp + (size_t)(it * 32) * HDD);
  __syncthreads();

#pragma unroll
  for (int ch = 0; ch < 8; ++ch) {
    // DMA next chunk into the other buffer (lands before the end barrier)
    if (ch < 7) {
      const u16* gs = vsrc + (ch + 1) * 4096 + w * 1024 + lane * 8;
      u16* ls = &vls[(ch + 1) & 1][0] + w * 1024;
      gload_lds16(gs, ls);
      gload_lds16(gs + 512, ls + 512);
    }

    const u16* vrow = &vls[ch & 1][0] + (l31 & 15) * 256;
    const int eb = l31 & 7;
#pragma unroll
    for (int it = 0; it < 8; ++it) {
      bfrag kf = kfr[it];
      if (ch < 7)    // rolling prefetch: next chunk's fragment, same slot
        kfr[it] = *(const bfrag*)(kp + (size_t)((ch + 1) * 256 + it * 32) * HDD);
      floatx16 d = __builtin_amdgcn_mfma_f32_32x32x16_bf16(kf, qf, z16, 0, 0, 0);
      u32 wr[8];
#pragma unroll
      for (int p = 0; p < 8; ++p)
        wr[p] = pack_bf(fexp2(d[2 * p]), fexp2(d[2 * p + 1]));
      const int cc0 = it * 4 + hl * 2;
      u32x4 af0 = *(const u32x4*)(vrow + ((cc0 ^ eb) << 3));
      u32x4 af1 = *(const u32x4*)(vrow + (((cc0 + 1) ^ eb) << 3));
      u32x4 ef0 = {wr[0], wr[1], wr[2], wr[3]};
      u32x4 ef1 = {wr[4], wr[5], wr[6], wr[7]};
      acc = __builtin_amdgcn_mfma_f32_32x32x16_bf16(
          __builtin_bit_cast(bfrag, af0), __builtin_bit_cast(bfrag, ef0), acc, 0, 0, 0);
      acc = __builtin_amdgcn_mfma_f32_32x32x16_bf16(
          __builtin_bit_cast(bfrag, af1), __builtin_bit_cast(bfrag, ef1), acc, 0, 0, 0);
    }
    __syncthreads();   // drains vmcnt -> next chunk's DMA is in LDS
  }

  // D[e][s]: col=l31 -> s; rows r=0..3 -> e=4hl+r, r=4..7 -> e=8+4hl+(r-4)
  float* ao = attp + (((size_t)tph * BB + b) * SS + s0 + l31) * (HH * HDD)
            + h * HDD + 4 * hl;
  float4 lo4 = {acc[0], acc[1], acc[2], acc[3]};
  float4 hi4 = {acc[4], acc[5], acc[6], acc[7]};
  *(float4*)ao       = lo4;
  *(float4*)(ao + 8) = hi4;
}

// ---------------------------------------------------------------------------
// K4: out_pre = (sum of 2 attended partials) @ Wo + bo, fused partial expsum
// over each block's 8 rows -> part[b][512][64].  Wo staged in LDS.
// ---------------------------------------------------------------------------
__global__ __launch_bounds__(256) void k_oproj(
    const float* __restrict__ att, const float* __restrict__ Wo,
    const float* __restrict__ bo, float* __restrict__ outp,
    float* __restrict__ part)
{
  __shared__ float wols[64 * 64];
  __shared__ float red[4][64];
  const int tid = threadIdx.x;
  const int blk = blockIdx.x;            // 2048
  const int b = blk >> 9, s0 = (blk & 511) << 3;
#pragma unroll
  for (int i = 0; i < 4; ++i)
    ((float4*)wols)[tid + 256 * i] = ((const float4*)Wo)[tid + 256 * i];
  __syncthreads();

  const int d = tid & 63, sg = tid >> 6;
  const float bov = bo[d];
  const size_t so = (size_t)BB * SS * 16;   // t-half stride in floatx4 units
  float es = 0.f;
#pragma unroll
  for (int r = 0; r < 2; ++r) {
    int s = s0 + sg * 2 + r;
    const floatx4* row = (const floatx4*)(att + ((size_t)b * SS + s) * 64);
    float acc = bov;
#pragma unroll
    for (int j = 0; j < 16; ++j) {
      floatx4 c = row[j] + row[j + so];
      acc += c[0] * wols[(4*j+0)*64 + d] + c[1] * wols[(4*j+1)*64 + d]
           + c[2] * wols[(4*j+2)*64 + d] + c[3] * wols[(4*j+3)*64 + d];
    }
    outp[((size_t)b * SS + s) * 64 + d] = acc;
    es += fexp2(acc * LOG2E);
  }
  red[sg][d] = es;
  __syncthreads();
  if (tid < 64)
    part[((size_t)b * 512 + (blk & 511)) * 64 + tid] =
        red[0][tid] + red[1][tid] + red[2][tid] + red[3][tid];
}

// ---------------------------------------------------------------------------
// K5: out = exp(out_pre) * rcp(sum_s exp(out_pre))  (512 partials per (b,d))
// ---------------------------------------------------------------------------
__global__ __launch_bounds__(256) void k_softmax(
    const float* __restrict__ outp, const float* __restrict__ part,
    float* __restrict__ out)
{
  __shared__ float red[4][64];
  __shared__ float rs[64];
  const int tid = threadIdx.x, d = tid & 63, sg = tid >> 6;
  const int st = blockIdx.x;             // 64 s-tiles of 64
  const int b = blockIdx.y;
  {
    float e = 0.f;
    const float* pp = part + ((size_t)b * 512 + sg * 128) * 64 + d;
#pragma unroll 8
    for (int c = 0; c < 128; ++c) e += pp[c * 64];
    red[sg][d] = e;
  }
  __syncthreads();
  if (tid < 64)
    rs[tid] = frcp(red[0][tid] + red[1][tid] + red[2][tid] + red[3][tid]);
  __syncthreads();
  const float r = rs[d];
  const size_t rowbase = ((size_t)b * SS + st * 64 + sg * 16) * 64 + d;
#pragma unroll 4
  for (int i = 0; i < 16; ++i)
    out[rowbase + i * 64] = fexp2(outp[rowbase + i * 64] * LOG2E) * r;
}

// ---------------------------------------------------------------------------
extern "C" void kernel_launch(void* const* d_in, const int* in_sizes, int n_in,
                              void* d_out, int out_size, void* d_ws, size_t ws_size,
                              hipStream_t stream) {
  const float* x  = (const float*)d_in[0];
  const float* Wq = (const float*)d_in[1];
  const float* bq = (const float*)d_in[2];
  const float* Wk = (const float*)d_in[3];
  const float* bk = (const float*)d_in[4];
  const float* Wv = (const float*)d_in[5];
  const float* bv = (const float*)d_in[6];
  const float* Wo = (const float*)d_in[7];
  const float* bo = (const float*)d_in[8];

  char* ws = (char*)d_ws;
  constexpr size_t QB_OFF  = 0;                    // 2 MiB u16
  constexpr size_t KB_OFF  = (size_t)2  << 20;     // 2 MiB u16
  constexpr size_t VF_OFF  = (size_t)4  << 20;     // 4 MiB f32
  constexpr size_t CSP_OFF = (size_t)8  << 20;     // 1 MiB f32 (4 partials)
  constexpr size_t VP_OFF  = (size_t)9  << 20;     // 2 MiB u16 (v' fragments)
  constexpr size_t ATT_OFF = (size_t)11 << 20;     // 8 MiB f32 (2 partials)
  constexpr size_t OUT_OFF = (size_t)19 << 20;     // 4 MiB f32
  constexpr size_t PT_OFF  = (size_t)23 << 20;     // 512 KiB f32

  u16*   qb   = (u16*)  (ws + QB_OFF);
  u16*   kb   = (u16*)  (ws + KB_OFF);
  float* vf   = (float*)(ws + VF_OFF);
  float* csp  = (float*)(ws + CSP_OFF);
  u16*   vpb  = (u16*)  (ws + VP_OFF);
  float* attp = (float*)(ws + ATT_OFF);
  float* outp = (float*)(ws + OUT_OFF);
  float* part = (float*)(ws + PT_OFF);
  float* out  = (float*)d_out;

  hipLaunchKernelGGL(k_proj,    dim3(1024),       dim3(256), 0, stream,
                     x, Wq, bq, Wk, bk, Wv, bv, qb, kb, vf);
  hipLaunchKernelGGL(k_colsum,  dim3(32, 4, 16),  dim3(256), 0, stream, qb, kb, csp);
  hipLaunchKernelGGL(k_vprep,   dim3(16, 16),     dim3(256), 0, stream, vf, csp, vpb);
  hipLaunchKernelGGL(k_attn,    dim3(32, 2, 16),  dim3(256), 0, stream,
                     qb, kb, vpb, attp);
  hipLaunchKernelGGL(k_oproj,   dim3(2048),       dim3(256), 0, stream,
                     attp, Wo, bo, outp, part);
  hipLaunchKernelGGL(k_softmax, dim3(64, 4),      dim3(256), 0, stream, outp, part, out);
}